// Round 1
// baseline (2726.040 us; speedup 1.0000x reference)
//
#include <hip/hip_runtime.h>

#define SEQ 8192
#define B   40
#define EMBD 64
#define HID 40
#define G4  160   // 4*HID
#define VOCAB 201

__device__ __forceinline__ float fexp2(float x) { float r; asm("v_exp_f32 %0, %1" : "=v"(r) : "v"(x)); return r; }
__device__ __forceinline__ float frcp (float x) { float r; asm("v_rcp_f32 %0, %1" : "=v"(r) : "v"(x)); return r; }

// sigmoid(x) = rcp(1+exp2(-x*log2e)) ; tanh(x) = 2*rcp(1+exp2(-2x*log2e)) - 1
#define LOG2E 1.4426950408889634f

// ---------------- kernel A: table[v][j] = enc_bih[j]+enc_bhh[j] + Wih[j,:]·emb[v,:] ----------------
__global__ void setup_kernel(const float* __restrict__ emb, const float* __restrict__ Wih,
                             const float* __restrict__ bih, const float* __restrict__ bhh,
                             float* __restrict__ table) {
    const int v = blockIdx.x;      // 0..200
    const int j = threadIdx.x;     // 0..159
    const float* er = emb + v * EMBD;
    const float* wr = Wih + j * EMBD;
    float acc = bih[j] + bhh[j];
#pragma unroll 8
    for (int e = 0; e < EMBD; ++e) acc = fmaf(er[e], wr[e], acc);
    table[v * G4 + j] = acc;
}

// ---------------- kernel B: encoder, 1 chain per block, 3 waves ----------------
__global__ __launch_bounds__(192, 1) void enc_kernel(const int* __restrict__ src,
                                                     const float* __restrict__ Whh,
                                                     const float* __restrict__ table,
                                                     float* __restrict__ est) {
    const int b    = blockIdx.x;
    const int tid  = threadIdx.x;
    const int lane = tid & 63;
    const int w    = tid >> 6;        // wave 0..2
    const int tt   = lane >> 4;       // gate type 0..3 (i,f,g,o)
    const int q    = lane & 15;
    const int e    = 16 * w + q;      // element 0..47 (valid < 40)
    const bool valid = (e < HID);
    const bool own   = valid && (tt == 0);
    const int j    = tt * HID + (valid ? e : 0);

    __shared__ int ssrc[SEQ];
    __shared__ __align__(16) float hbuf[2][48];

    // stage this chain's source column into LDS
    for (int t = tid; t < SEQ; t += 192) ssrc[t] = src[t * B + b];

    // load Whh row j (40 floats) into registers
    float4 wr4[10];
#pragma unroll
    for (int r = 0; r < 10; ++r) {
        float4 t4 = *reinterpret_cast<const float4*>(&Whh[j * HID + 4 * r]);
        if (!valid) t4 = make_float4(0.f, 0.f, 0.f, 0.f);
        wr4[r] = t4;
    }
    const float mcoef = (tt == 2) ? (-2.f * LOG2E) : (-LOG2E);
    const float vsc   = (tt == 2) ? 2.f : 1.f;
    const float voff  = (tt == 2) ? -1.f : 0.f;

    float4 hr4[10];
#pragma unroll
    for (int r = 0; r < 10; ++r) hr4[r] = make_float4(0.f, 0.f, 0.f, 0.f);
    float c = 0.f, h = 0.f;

    __syncthreads();

    int  idx0 = ssrc[0];
    float tv  = valid ? table[idx0 * G4 + j] : 0.f;   // input-gate value for t=0
    int  idxn = ssrc[1];

    for (int t = 0; t < SEQ; ++t) {
        // prefetch table row for t+1 and source index for t+2
        float tvn  = valid ? table[idxn * G4 + j] : 0.f;
        int   idn2 = ssrc[(t + 2) & (SEQ - 1)];

        // gates: acc = table (x-part + bias) + Whh[j,:]·h
        float a0 = tv, a1 = 0.f, a2 = 0.f, a3 = 0.f;
#pragma unroll
        for (int r = 0; r < 10; ++r) {
            a0 = fmaf(wr4[r].x, hr4[r].x, a0);
            a1 = fmaf(wr4[r].y, hr4[r].y, a1);
            a2 = fmaf(wr4[r].z, hr4[r].z, a2);
            a3 = fmaf(wr4[r].w, hr4[r].w, a3);
        }
        float xg = (a0 + a1) + (a2 + a3);

        // activation: sigmoid for i,f,o ; tanh for g
        float E   = fexp2(mcoef * xg);
        float v   = frcp(1.f + E);
        float act = fmaf(vsc, v, voff);

        // gather the 4 gates for my element (all within this wave)
        float ig = __shfl(act, q);
        float fg = __shfl(act, q + 16);
        float gg = __shfl(act, q + 32);
        float og = __shfl(act, q + 48);

        c = fmaf(fg, c, ig * gg);
        float Ec = fexp2(-2.f * LOG2E * c);
        float th = fmaf(2.f, frcp(1.f + Ec), -1.f);
        h = og * th;

        // publish h, one barrier, reload replicated h
        if (own) hbuf[t & 1][e] = h;
        __syncthreads();
#pragma unroll
        for (int r = 0; r < 10; ++r)
            hr4[r] = *reinterpret_cast<const float4*>(&hbuf[t & 1][4 * r]);

        tv = tvn; idxn = idn2;
    }

    if (own) {
        est[b * 80 + e]       = h;
        est[b * 80 + HID + e] = c;
    }
}

// ---------------- kernel C: decoder, 40 steps, 1 chain per block ----------------
__global__ __launch_bounds__(192, 1) void dec_kernel(const float* __restrict__ dinp,
                                                     const float* __restrict__ Wih,
                                                     const float* __restrict__ Whh,
                                                     const float* __restrict__ bih,
                                                     const float* __restrict__ bhh,
                                                     const float* __restrict__ est,
                                                     float* __restrict__ out) {
    const int b    = blockIdx.x;
    const int tid  = threadIdx.x;
    const int lane = tid & 63;
    const int w    = tid >> 6;
    const int tt   = lane >> 4;
    const int q    = lane & 15;
    const int e    = 16 * w + q;
    const bool valid = (e < HID);
    const bool own   = valid && (tt == 0);
    const int j    = tt * HID + (valid ? e : 0);

    __shared__ __align__(16) float hbuf[2][48];

    float4 wi4[10], wh4[10];
#pragma unroll
    for (int r = 0; r < 10; ++r) {
        float4 ti = *reinterpret_cast<const float4*>(&Wih[j * HID + 4 * r]);
        float4 th = *reinterpret_cast<const float4*>(&Whh[j * HID + 4 * r]);
        if (!valid) { ti = make_float4(0,0,0,0); th = make_float4(0,0,0,0); }
        wi4[r] = ti; wh4[r] = th;
    }
    const float bj = valid ? (bih[j] + bhh[j]) : 0.f;

    const float mcoef = (tt == 2) ? (-2.f * LOG2E) : (-LOG2E);
    const float vsc   = (tt == 2) ? 2.f : 1.f;
    const float voff  = (tt == 2) ? -1.f : 0.f;

    float4 xr4[10], hr4[10];
#pragma unroll
    for (int r = 0; r < 10; ++r) {
        xr4[r] = *reinterpret_cast<const float4*>(&dinp[b * HID + 4 * r]);
        hr4[r] = *reinterpret_cast<const float4*>(&est[b * 80 + 4 * r]);
    }
    float c = valid ? est[b * 80 + HID + e] : 0.f;

    for (int t = 0; t < B; ++t) {
        float a0 = bj, a1 = 0.f, a2 = 0.f, a3 = 0.f;
#pragma unroll
        for (int r = 0; r < 10; ++r) {
            a0 = fmaf(wi4[r].x, xr4[r].x, a0);
            a1 = fmaf(wi4[r].y, xr4[r].y, a1);
            a2 = fmaf(wi4[r].z, xr4[r].z, a2);
            a3 = fmaf(wi4[r].w, xr4[r].w, a3);
            a0 = fmaf(wh4[r].x, hr4[r].x, a0);
            a1 = fmaf(wh4[r].y, hr4[r].y, a1);
            a2 = fmaf(wh4[r].z, hr4[r].z, a2);
            a3 = fmaf(wh4[r].w, hr4[r].w, a3);
        }
        float xg = (a0 + a1) + (a2 + a3);

        float E   = fexp2(mcoef * xg);
        float v   = frcp(1.f + E);
        float act = fmaf(vsc, v, voff);

        float ig = __shfl(act, q);
        float fg = __shfl(act, q + 16);
        float gg = __shfl(act, q + 32);
        float og = __shfl(act, q + 48);

        c = fmaf(fg, c, ig * gg);
        float Ec = fexp2(-2.f * LOG2E * c);
        float th = fmaf(2.f, frcp(1.f + Ec), -1.f);
        float h  = og * th;

        if (own) out[(t * B + b) * HID + e] = h;

        if (own) hbuf[t & 1][e] = h;
        __syncthreads();
#pragma unroll
        for (int r = 0; r < 10; ++r) {
            hr4[r] = *reinterpret_cast<const float4*>(&hbuf[t & 1][4 * r]);
            xr4[r] = hr4[r];   // next input is current output
        }
    }
}

extern "C" void kernel_launch(void* const* d_in, const int* in_sizes, int n_in,
                              void* d_out, int out_size, void* d_ws, size_t ws_size,
                              hipStream_t stream) {
    const int*   src  = (const int*)  d_in[0];
    const float* dinp = (const float*)d_in[1];
    const float* emb  = (const float*)d_in[2];
    const float* eWih = (const float*)d_in[3];
    const float* eWhh = (const float*)d_in[4];
    const float* ebih = (const float*)d_in[5];
    const float* ebhh = (const float*)d_in[6];
    const float* dWih = (const float*)d_in[7];
    const float* dWhh = (const float*)d_in[8];
    const float* dbih = (const float*)d_in[9];
    const float* dbhh = (const float*)d_in[10];
    float* out = (float*)d_out;

    float* table = (float*)d_ws;          // 201*160 floats
    float* est   = table + VOCAB * G4;    // 40*80 floats (h then c per batch)

    hipLaunchKernelGGL(setup_kernel, dim3(VOCAB), dim3(G4), 0, stream, emb, eWih, ebih, ebhh, table);
    hipLaunchKernelGGL(enc_kernel,   dim3(B),     dim3(192), 0, stream, src, eWhh, table, est);
    hipLaunchKernelGGL(dec_kernel,   dim3(B),     dim3(192), 0, stream, dinp, dWih, dWhh, dbih, dbhh, est, out);
}

// Round 2
// 2626.378 us; speedup vs baseline: 1.0379x; 1.0379x over previous
//
#include <hip/hip_runtime.h>

#define SEQ 8192
#define B   40
#define EMBD 64
#define HID 40
#define G4  160   // 4*HID
#define VOCAB 201
#define LOG2E 1.4426950408889634f

typedef float v2f __attribute__((ext_vector_type(2)));

__device__ __forceinline__ float fexp2(float x) { float r; asm("v_exp_f32 %0, %1" : "=v"(r) : "v"(x)); return r; }
__device__ __forceinline__ float frcp (float x) { float r; asm("v_rcp_f32 %0, %1" : "=v"(r) : "v"(x)); return r; }
__device__ __forceinline__ float sigm (float x) { return frcp(1.f + fexp2(-LOG2E * x)); }
__device__ __forceinline__ float tanh_(float x) { return fmaf(2.f, frcp(1.f + fexp2(-2.f * LOG2E * x)), -1.f); }

// ---------------- kernel A: table4[v][e] = (i,f,g,o) gate x-parts+bias for vocab v, element e ----------------
__global__ void setup_kernel(const float* __restrict__ emb, const float* __restrict__ Wih,
                             const float* __restrict__ bih, const float* __restrict__ bhh,
                             float4* __restrict__ table4) {
    const int v = blockIdx.x;          // 0..200
    const int e = threadIdx.x;         // 0..63, active < 40
    if (e >= HID) return;
    const float* er = emb + v * EMBD;
    float acc[4];
#pragma unroll
    for (int g = 0; g < 4; ++g) {
        const int j = g * HID + e;
        const float* wr = Wih + j * EMBD;
        float a = bih[j] + bhh[j];
#pragma unroll 8
        for (int k = 0; k < EMBD; ++k) a = fmaf(er[k], wr[k], a);
        acc[g] = a;
    }
    table4[v * HID + e] = make_float4(acc[0], acc[1], acc[2], acc[3]);
}

// ---------------- kernel B: encoder, 1 chain per block, ONE wave ----------------
__global__ __launch_bounds__(64, 1) void enc_kernel(const int* __restrict__ src,
                                                    const float* __restrict__ Whh,
                                                    const float4* __restrict__ tbl,
                                                    float* __restrict__ est) {
    const int b    = blockIdx.x;
    const int lane = threadIdx.x;
    const int e    = (lane < HID) ? lane : 0;   // clamp for idle lanes

    __shared__ int ssrc[SEQ];
    __shared__ __align__(16) float hlds[64];

    // stage this chain's source column into LDS
    for (int t = lane; t < SEQ; t += 64) ssrc[t] = src[t * B + b];

    // load Whh rows for gates i,f,g,o of element e, as packed float2
    v2f wi[20], wf[20], wg[20], wo[20];
#pragma unroll
    for (int r = 0; r < 10; ++r) {
        float4 a = *reinterpret_cast<const float4*>(&Whh[(0 * HID + e) * HID + 4 * r]);
        float4 bq= *reinterpret_cast<const float4*>(&Whh[(1 * HID + e) * HID + 4 * r]);
        float4 cq= *reinterpret_cast<const float4*>(&Whh[(2 * HID + e) * HID + 4 * r]);
        float4 dq= *reinterpret_cast<const float4*>(&Whh[(3 * HID + e) * HID + 4 * r]);
        wi[2*r] = (v2f){a.x, a.y};  wi[2*r+1] = (v2f){a.z, a.w};
        wf[2*r] = (v2f){bq.x, bq.y}; wf[2*r+1] = (v2f){bq.z, bq.w};
        wg[2*r] = (v2f){cq.x, cq.y}; wg[2*r+1] = (v2f){cq.z, cq.w};
        wo[2*r] = (v2f){dq.x, dq.y}; wo[2*r+1] = (v2f){dq.z, dq.w};
    }

    v2f hv[20];
#pragma unroll
    for (int r = 0; r < 20; ++r) hv[r] = (v2f){0.f, 0.f};
    float c = 0.f, h = 0.f;

    __syncthreads();   // staging of ssrc done (single wave; cheap)

    int iA = ssrc[0], iB = ssrc[1], iC = ssrc[2];
    float4 ta = tbl[iA * HID + e];     // x-part for t
    float4 tb = tbl[iB * HID + e];     // x-part for t+1

    for (int t = 0; t < SEQ; ++t) {
        // prefetch x-part for t+2 and index for t+3
        float4 tc = tbl[iC * HID + e];
        iC = ssrc[(t + 3) & (SEQ - 1)];

        // 4 gate dots over h (packed fp32)
        v2f ai = (v2f){0.f, 0.f}, af = ai, ag = ai, ao = ai;
#pragma unroll
        for (int r = 0; r < 20; ++r) {
            ai = __builtin_elementwise_fma(wi[r], hv[r], ai);
            af = __builtin_elementwise_fma(wf[r], hv[r], af);
            ag = __builtin_elementwise_fma(wg[r], hv[r], ag);
            ao = __builtin_elementwise_fma(wo[r], hv[r], ao);
        }
        float gi = ta.x + ai.x + ai.y;
        float gf = ta.y + af.x + af.y;
        float gg = ta.z + ag.x + ag.y;
        float go = ta.w + ao.x + ao.y;

        float si = sigm(gi), sf = sigm(gf), tg = tanh_(gg), so = sigm(go);
        c = fmaf(sf, c, si * tg);
        h = so * tanh_(c);

        // publish h (single wave: LDS pipe is in-order, no barrier)
        hlds[lane] = h;
#pragma unroll
        for (int r = 0; r < 10; ++r) {
            float4 x = *reinterpret_cast<const float4*>(&hlds[4 * r]);  // broadcast read
            hv[2*r]   = (v2f){x.x, x.y};
            hv[2*r+1] = (v2f){x.z, x.w};
        }

        ta = tb; tb = tc;
    }

    if (lane < HID) {
        est[b * 80 + lane]       = h;
        est[b * 80 + HID + lane] = c;
    }
}

// ---------------- kernel C: decoder, 40 steps, 1 chain per block (3 waves, proven) ----------------
__global__ __launch_bounds__(192, 1) void dec_kernel(const float* __restrict__ dinp,
                                                     const float* __restrict__ Wih,
                                                     const float* __restrict__ Whh,
                                                     const float* __restrict__ bih,
                                                     const float* __restrict__ bhh,
                                                     const float* __restrict__ est,
                                                     float* __restrict__ out) {
    const int b    = blockIdx.x;
    const int tid  = threadIdx.x;
    const int lane = tid & 63;
    const int w    = tid >> 6;
    const int tt   = lane >> 4;
    const int q    = lane & 15;
    const int e    = 16 * w + q;
    const bool valid = (e < HID);
    const bool own   = valid && (tt == 0);
    const int j    = tt * HID + (valid ? e : 0);

    __shared__ __align__(16) float hbuf[2][48];

    float4 wi4[10], wh4[10];
#pragma unroll
    for (int r = 0; r < 10; ++r) {
        float4 ti = *reinterpret_cast<const float4*>(&Wih[j * HID + 4 * r]);
        float4 th = *reinterpret_cast<const float4*>(&Whh[j * HID + 4 * r]);
        if (!valid) { ti = make_float4(0,0,0,0); th = make_float4(0,0,0,0); }
        wi4[r] = ti; wh4[r] = th;
    }
    const float bj = valid ? (bih[j] + bhh[j]) : 0.f;

    const float mcoef = (tt == 2) ? (-2.f * LOG2E) : (-LOG2E);
    const float vsc   = (tt == 2) ? 2.f : 1.f;
    const float voff  = (tt == 2) ? -1.f : 0.f;

    float4 xr4[10], hr4[10];
#pragma unroll
    for (int r = 0; r < 10; ++r) {
        xr4[r] = *reinterpret_cast<const float4*>(&dinp[b * HID + 4 * r]);
        hr4[r] = *reinterpret_cast<const float4*>(&est[b * 80 + 4 * r]);
    }
    float c = valid ? est[b * 80 + HID + e] : 0.f;

    for (int t = 0; t < B; ++t) {
        float a0 = bj, a1 = 0.f, a2 = 0.f, a3 = 0.f;
#pragma unroll
        for (int r = 0; r < 10; ++r) {
            a0 = fmaf(wi4[r].x, xr4[r].x, a0);
            a1 = fmaf(wi4[r].y, xr4[r].y, a1);
            a2 = fmaf(wi4[r].z, xr4[r].z, a2);
            a3 = fmaf(wi4[r].w, xr4[r].w, a3);
            a0 = fmaf(wh4[r].x, hr4[r].x, a0);
            a1 = fmaf(wh4[r].y, hr4[r].y, a1);
            a2 = fmaf(wh4[r].z, hr4[r].z, a2);
            a3 = fmaf(wh4[r].w, hr4[r].w, a3);
        }
        float xg = (a0 + a1) + (a2 + a3);

        float E   = fexp2(mcoef * xg);
        float v   = frcp(1.f + E);
        float act = fmaf(vsc, v, voff);

        float ig = __shfl(act, q);
        float fg = __shfl(act, q + 16);
        float gg = __shfl(act, q + 32);
        float og = __shfl(act, q + 48);

        c = fmaf(fg, c, ig * gg);
        float Ec = fexp2(-2.f * LOG2E * c);
        float th = fmaf(2.f, frcp(1.f + Ec), -1.f);
        float h  = og * th;

        if (own) out[(t * B + b) * HID + e] = h;

        if (own) hbuf[t & 1][e] = h;
        __syncthreads();
#pragma unroll
        for (int r = 0; r < 10; ++r) {
            hr4[r] = *reinterpret_cast<const float4*>(&hbuf[t & 1][4 * r]);
            xr4[r] = hr4[r];   // next input is current output
        }
    }
}

extern "C" void kernel_launch(void* const* d_in, const int* in_sizes, int n_in,
                              void* d_out, int out_size, void* d_ws, size_t ws_size,
                              hipStream_t stream) {
    const int*   src  = (const int*)  d_in[0];
    const float* dinp = (const float*)d_in[1];
    const float* emb  = (const float*)d_in[2];
    const float* eWih = (const float*)d_in[3];
    const float* eWhh = (const float*)d_in[4];
    const float* ebih = (const float*)d_in[5];
    const float* ebhh = (const float*)d_in[6];
    const float* dWih = (const float*)d_in[7];
    const float* dWhh = (const float*)d_in[8];
    const float* dbih = (const float*)d_in[9];
    const float* dbhh = (const float*)d_in[10];
    float* out = (float*)d_out;

    float4* table4 = (float4*)d_ws;                       // 201*40 float4
    float*  est    = (float*)(table4 + VOCAB * HID);      // 40*80 floats

    hipLaunchKernelGGL(setup_kernel, dim3(VOCAB), dim3(64), 0, stream, emb, eWih, ebih, ebhh, table4);
    hipLaunchKernelGGL(enc_kernel,   dim3(B),     dim3(64), 0, stream, src, eWhh, table4, est);
    hipLaunchKernelGGL(dec_kernel,   dim3(B),     dim3(192), 0, stream, dinp, dWih, dWhh, dbih, dbhh, est, out);
}

// Round 3
// 2532.389 us; speedup vs baseline: 1.0765x; 1.0371x over previous
//
#include <hip/hip_runtime.h>
#include <stdint.h>

#define SEQ 8192
#define B   40
#define EMBD 64
#define HID 40
#define VOCAB 201
#define LOG2E 1.4426950408889634f

typedef float v2f __attribute__((ext_vector_type(2)));

__device__ __forceinline__ float fexp2(float x) { float r; asm("v_exp_f32 %0, %1" : "=v"(r) : "v"(x)); return r; }
__device__ __forceinline__ float frcp (float x) { float r; asm("v_rcp_f32 %0, %1" : "=v"(r) : "v"(x)); return r; }
__device__ __forceinline__ float sigm (float x) { return frcp(1.f + fexp2(-LOG2E * x)); }
__device__ __forceinline__ float tanh_(float x) { return fmaf(2.f, frcp(1.f + fexp2(-2.f * LOG2E * x)), -1.f); }
__device__ __forceinline__ float rdlane(float v, int k) {
    int r = __builtin_amdgcn_readlane(__builtin_bit_cast(int, v), k);
    return __builtin_bit_cast(float, r);
}

// ---------------- kernel A: table4[v][e] = (i,f,g,o) gate x-parts+bias ----------------
__global__ void setup_kernel(const float* __restrict__ emb, const float* __restrict__ Wih,
                             const float* __restrict__ bih, const float* __restrict__ bhh,
                             float4* __restrict__ table4) {
    const int v = blockIdx.x;          // 0..200
    const int e = threadIdx.x;         // 0..63, active < 40
    if (e >= HID) return;
    const float* er = emb + v * EMBD;
    float acc[4];
#pragma unroll
    for (int g = 0; g < 4; ++g) {
        const int j = g * HID + e;
        const float* wr = Wih + j * EMBD;
        float a = bih[j] + bhh[j];
#pragma unroll 8
        for (int k = 0; k < EMBD; ++k) a = fmaf(er[k], wr[k], a);
        acc[g] = a;
    }
    table4[v * HID + e] = make_float4(acc[0], acc[1], acc[2], acc[3]);
}

// ---------------- kernel B: encoder, 1 chain per block, ONE wave, readlane broadcast ----------------
__global__ __launch_bounds__(64, 1) void enc_kernel(const int* __restrict__ src,
                                                    const float* __restrict__ Whh,
                                                    const float4* __restrict__ tbl,
                                                    float* __restrict__ est) {
    const int b    = blockIdx.x;
    const int lane = threadIdx.x;
    const int e    = (lane < HID) ? lane : 0;   // clamp idle lanes to element 0

    __shared__ int ssrc[SEQ];
    for (int t = lane; t < SEQ; t += 64) ssrc[t] = src[t * B + b];

    // weights packed per lane: wif[k]=(Wi[e][k],Wf[e][k]), wgo[k]=(Wg[e][k],Wo[e][k])
    v2f wif[40], wgo[40];
#pragma unroll
    for (int r = 0; r < 10; ++r) {
        float4 ai = *reinterpret_cast<const float4*>(&Whh[(0 * HID + e) * HID + 4 * r]);
        float4 af = *reinterpret_cast<const float4*>(&Whh[(1 * HID + e) * HID + 4 * r]);
        float4 ag = *reinterpret_cast<const float4*>(&Whh[(2 * HID + e) * HID + 4 * r]);
        float4 ao = *reinterpret_cast<const float4*>(&Whh[(3 * HID + e) * HID + 4 * r]);
        wif[4*r+0] = (v2f){ai.x, af.x}; wif[4*r+1] = (v2f){ai.y, af.y};
        wif[4*r+2] = (v2f){ai.z, af.z}; wif[4*r+3] = (v2f){ai.w, af.w};
        wgo[4*r+0] = (v2f){ag.x, ao.x}; wgo[4*r+1] = (v2f){ag.y, ao.y};
        wgo[4*r+2] = (v2f){ag.z, ao.z}; wgo[4*r+3] = (v2f){ag.w, ao.w};
    }

    float c = 0.f, h = 0.f;
    __syncthreads();   // ssrc staged (single wave, cheap)

    int i0 = ssrc[0], i1 = ssrc[1], i2 = ssrc[2], i3 = ssrc[3];
    float4 tq0 = tbl[i0 * HID + e];
    float4 tq1 = tbl[i1 * HID + e];
    float4 tq2 = tbl[i2 * HID + e];

#pragma unroll 4
    for (int t = 0; t < SEQ; ++t) {
        // prefetch x-part for t+3, index for t+4
        float4 tq3 = tbl[i3 * HID + e];
        i3 = ssrc[(t + 4) & (SEQ - 1)];

        v2f aif0 = (v2f){tq0.x, tq0.y}, aif1 = (v2f){0.f,0.f}, aif2 = (v2f){0.f,0.f}, aif3 = (v2f){0.f,0.f};
        v2f ago0 = (v2f){tq0.z, tq0.w}, ago1 = (v2f){0.f,0.f}, ago2 = (v2f){0.f,0.f}, ago3 = (v2f){0.f,0.f};
#pragma unroll
        for (int k = 0; k < 40; k += 4) {
            float h0 = rdlane(h, k + 0);
            float h1 = rdlane(h, k + 1);
            float h2 = rdlane(h, k + 2);
            float h3 = rdlane(h, k + 3);
            aif0 = __builtin_elementwise_fma(wif[k+0], (v2f){h0, h0}, aif0);
            ago0 = __builtin_elementwise_fma(wgo[k+0], (v2f){h0, h0}, ago0);
            aif1 = __builtin_elementwise_fma(wif[k+1], (v2f){h1, h1}, aif1);
            ago1 = __builtin_elementwise_fma(wgo[k+1], (v2f){h1, h1}, ago1);
            aif2 = __builtin_elementwise_fma(wif[k+2], (v2f){h2, h2}, aif2);
            ago2 = __builtin_elementwise_fma(wgo[k+2], (v2f){h2, h2}, ago2);
            aif3 = __builtin_elementwise_fma(wif[k+3], (v2f){h3, h3}, aif3);
            ago3 = __builtin_elementwise_fma(wgo[k+3], (v2f){h3, h3}, ago3);
        }
        v2f AIF = (aif0 + aif1) + (aif2 + aif3);
        v2f AGO = (ago0 + ago1) + (ago2 + ago3);

        float si = sigm(AIF.x), sf = sigm(AIF.y);
        float tg = tanh_(AGO.x), so = sigm(AGO.y);
        c = fmaf(sf, c, si * tg);
        h = so * tanh_(c);

        tq0 = tq1; tq1 = tq2; tq2 = tq3;
    }

    if (lane < HID) {
        est[b * 80 + lane]       = h;
        est[b * 80 + HID + lane] = c;
    }
}

// ---------------- kernel C: decoder, 40 steps, 1 chain per block (3 waves, proven) ----------------
__global__ __launch_bounds__(192, 1) void dec_kernel(const float* __restrict__ dinp,
                                                     const float* __restrict__ Wih,
                                                     const float* __restrict__ Whh,
                                                     const float* __restrict__ bih,
                                                     const float* __restrict__ bhh,
                                                     const float* __restrict__ est,
                                                     float* __restrict__ out) {
    const int b    = blockIdx.x;
    const int tid  = threadIdx.x;
    const int lane = tid & 63;
    const int w    = tid >> 6;
    const int tt   = lane >> 4;
    const int q    = lane & 15;
    const int e    = 16 * w + q;
    const bool valid = (e < HID);
    const bool own   = valid && (tt == 0);
    const int j    = tt * HID + (valid ? e : 0);

    __shared__ __align__(16) float hbuf[2][48];

    float4 wi4[10], wh4[10];
#pragma unroll
    for (int r = 0; r < 10; ++r) {
        float4 ti = *reinterpret_cast<const float4*>(&Wih[j * HID + 4 * r]);
        float4 th = *reinterpret_cast<const float4*>(&Whh[j * HID + 4 * r]);
        if (!valid) { ti = make_float4(0,0,0,0); th = make_float4(0,0,0,0); }
        wi4[r] = ti; wh4[r] = th;
    }
    const float bj = valid ? (bih[j] + bhh[j]) : 0.f;

    const float mcoef = (tt == 2) ? (-2.f * LOG2E) : (-LOG2E);
    const float vsc   = (tt == 2) ? 2.f : 1.f;
    const float voff  = (tt == 2) ? -1.f : 0.f;

    float4 xr4[10], hr4[10];
#pragma unroll
    for (int r = 0; r < 10; ++r) {
        xr4[r] = *reinterpret_cast<const float4*>(&dinp[b * HID + 4 * r]);
        hr4[r] = *reinterpret_cast<const float4*>(&est[b * 80 + 4 * r]);
    }
    float c = valid ? est[b * 80 + HID + e] : 0.f;

    for (int t = 0; t < B; ++t) {
        float a0 = bj, a1 = 0.f, a2 = 0.f, a3 = 0.f;
#pragma unroll
        for (int r = 0; r < 10; ++r) {
            a0 = fmaf(wi4[r].x, xr4[r].x, a0);
            a1 = fmaf(wi4[r].y, xr4[r].y, a1);
            a2 = fmaf(wi4[r].z, xr4[r].z, a2);
            a3 = fmaf(wi4[r].w, xr4[r].w, a3);
            a0 = fmaf(wh4[r].x, hr4[r].x, a0);
            a1 = fmaf(wh4[r].y, hr4[r].y, a1);
            a2 = fmaf(wh4[r].z, hr4[r].z, a2);
            a3 = fmaf(wh4[r].w, hr4[r].w, a3);
        }
        float xg = (a0 + a1) + (a2 + a3);

        float E   = fexp2(mcoef * xg);
        float v   = frcp(1.f + E);
        float act = fmaf(vsc, v, voff);

        float ig = __shfl(act, q);
        float fg = __shfl(act, q + 16);
        float gg = __shfl(act, q + 32);
        float og = __shfl(act, q + 48);

        c = fmaf(fg, c, ig * gg);
        float Ec = fexp2(-2.f * LOG2E * c);
        float th = fmaf(2.f, frcp(1.f + Ec), -1.f);
        float h  = og * th;

        if (own) out[(t * B + b) * HID + e] = h;

        if (own) hbuf[t & 1][e] = h;
        __syncthreads();
#pragma unroll
        for (int r = 0; r < 10; ++r) {
            hr4[r] = *reinterpret_cast<const float4*>(&hbuf[t & 1][4 * r]);
            xr4[r] = hr4[r];   // next input is current output
        }
    }
}

extern "C" void kernel_launch(void* const* d_in, const int* in_sizes, int n_in,
                              void* d_out, int out_size, void* d_ws, size_t ws_size,
                              hipStream_t stream) {
    const int*   src  = (const int*)  d_in[0];
    const float* dinp = (const float*)d_in[1];
    const float* emb  = (const float*)d_in[2];
    const float* eWih = (const float*)d_in[3];
    const float* eWhh = (const float*)d_in[4];
    const float* ebih = (const float*)d_in[5];
    const float* ebhh = (const float*)d_in[6];
    const float* dWih = (const float*)d_in[7];
    const float* dWhh = (const float*)d_in[8];
    const float* dbih = (const float*)d_in[9];
    const float* dbhh = (const float*)d_in[10];
    float* out = (float*)d_out;

    float4* table4 = (float4*)d_ws;                       // 201*40 float4
    float*  est    = (float*)(table4 + VOCAB * HID);      // 40*80 floats

    hipLaunchKernelGGL(setup_kernel, dim3(VOCAB), dim3(64), 0, stream, emb, eWih, ebih, ebhh, table4);
    hipLaunchKernelGGL(enc_kernel,   dim3(B),     dim3(64), 0, stream, src, eWhh, table4, est);
    hipLaunchKernelGGL(dec_kernel,   dim3(B),     dim3(192), 0, stream, dinp, dWih, dWhh, dbih, dbhh, est, out);
}